// Round 11
// baseline (259.439 us; speedup 1.0000x reference)
//
#include <hip/hip_runtime.h>
#include <math.h>

#define BATCH 8
#define SEQ 1024
#define D_MODEL 512
#define D_INNER 1024
#define D_STATE 16
#define DT_RANK 32
#define NROWS (BATCH * SEQ)   // 8192
#define CH 64                 // chunks per sequence
#define CL 16                 // chunk length
#define USLAB 8388608l        // 8192*1024 elems (one dir slab)

typedef short short8 __attribute__((ext_vector_type(8)));
typedef float f32x4 __attribute__((ext_vector_type(4)));

__device__ __forceinline__ float sigmoidf_(float x) { return 1.f / (1.f + __expf(-x)); }

// fast softplus: hw-approx v_exp+v_log, rel err ~1e-6 << bf16 rounding (R10 win)
__device__ __forceinline__ float softplus_(float v) {
  return (v > 20.f) ? v : __logf(1.f + __expf(v));
}

__device__ __forceinline__ ushort f2b(float f) {  // fp32 -> bf16 RNE
  uint u = __float_as_uint(f);
  return (ushort)((u + 0x7FFFu + ((u >> 16) & 1u)) >> 16);
}
__device__ __forceinline__ float b2f(ushort u) {
  return __uint_as_float(((uint)u) << 16);
}

__device__ __forceinline__ void gload16(const ushort* g, const ushort* l) {
  __builtin_amdgcn_global_load_lds(
      (const __attribute__((address_space(1))) void*)g,
      (__attribute__((address_space(3))) void*)l, 16, 0, 0);
}

__device__ __forceinline__ int revrow(int m) {
  return (m & ~1023) | (1023 - (m & 1023));
}

// ========== in_proj: 256x256 tile, 8 waves, counted-vmcnt pipeline =========
// T3/T4/T5: triple-buffered LDS, 2 K-tiles prefetch depth, vmcnt(4) steady
// state (never 0 in loop), raw s_barrier (NO __syncthreads: it drains vmcnt),
// setprio around MFMA clusters. 2 phases per K-tile, 16 MFMA each.
// EPI=2 semantics: n -> {dir, u|z}; bwd rows reversed; z gets silu.
__global__ __launch_bounds__(512, 2) void inproj256(
    const ushort* __restrict__ A, int lda,      // [8192][512]
    const ushort* __restrict__ B, int ldb,      // [4096][512]
    ushort* __restrict__ Cu, ushort* __restrict__ Cz,
    int K)
{
  __shared__ ushort As[3][256 * 32];
  __shared__ ushort Bs[3][256 * 32];
  const int tid = threadIdx.x;
  const int w = tid >> 6, lane = tid & 63;

  const int nwg = gridDim.x * gridDim.y;        // %8 == 0
  int bid = blockIdx.y * gridDim.x + blockIdx.x;
  int wgid = (bid & 7) * (nwg >> 3) + (bid >> 3);
  const int bm = (wgid / gridDim.x) * 256;
  const int bn = (wgid % gridDim.x) * 256;

  const int wr = w >> 2, wc = w & 3;            // 2x4 wave grid
  const int rw0 = wr * 128, cw0 = wc * 64;      // per-wave 128x64 output
  const int srow = w * 16 + (lane >> 2);        // staging: 8 waves cover 128 rows
  const int scol = (((lane & 3) ^ ((lane >> 3) & 3)) << 3);   // src chunk swizzle
  const int rchunk = (((lane >> 4) ^ (((lane & 15) >> 1) & 3)) << 3);

  f32x4 acc[8][4] = {};

  auto stageA = [&](int buf, int k0, int half) {
    int gm = bm + half * 128 + srow;
    gload16(A + (long)gm * lda + k0 + scol, &As[buf][(half * 128 + w * 16) * 32]);
  };
  auto stageB = [&](int buf, int k0, int half) {
    int gn = bn + half * 128 + srow;
    gload16(B + (long)gn * ldb + k0 + scol, &Bs[buf][(half * 128 + w * 16) * 32]);
  };

  const int NT = K >> 5;                         // 16 for K=512
  // prologue: stage tiles 0 and 1 (4 loads/thread each)
  stageA(0, 0, 0); stageA(0, 0, 1); stageB(0, 0, 0); stageB(0, 0, 1);
  stageA(1, 32, 0); stageA(1, 32, 1); stageB(1, 32, 0); stageB(1, 32, 1);
  asm volatile("s_waitcnt vmcnt(4)" ::: "memory");   // tile 0 certified
  __builtin_amdgcn_s_barrier();

  int buf = 0;
  for (int t = 0; t < NT; ++t) {
    const int kf = (t + 2) << 5;
    const int sbuf = (buf >= 1) ? buf - 1 : buf + 2;   // (buf+2)%3
    // ---- phase 1: ds_read a0/b0 | stage A(t+2) | barrier | 16 MFMA ----
    short8 a0[4], b0[4];
#pragma unroll
    for (int i = 0; i < 4; ++i)
      a0[i] = *(const short8*)&As[buf][(rw0 + i * 16 + (lane & 15)) * 32 + rchunk];
#pragma unroll
    for (int j = 0; j < 4; ++j)
      b0[j] = *(const short8*)&Bs[buf][(cw0 + j * 16 + (lane & 15)) * 32 + rchunk];
    if (t + 2 < NT) { stageA(sbuf, kf, 0); stageA(sbuf, kf, 1); }
    __builtin_amdgcn_s_barrier();
    __builtin_amdgcn_s_setprio(1);
#pragma unroll
    for (int i = 0; i < 4; ++i)
#pragma unroll
      for (int j = 0; j < 4; ++j)
        acc[i][j] = __builtin_amdgcn_mfma_f32_16x16x32_bf16(a0[i], b0[j], acc[i][j], 0, 0, 0);
    __builtin_amdgcn_s_setprio(0);
    __builtin_amdgcn_s_barrier();
    // ---- phase 2: ds_read a1 | stage B(t+2) | vmcnt | barrier | 16 MFMA ----
    short8 a1[4];
#pragma unroll
    for (int i = 0; i < 4; ++i)
      a1[i] = *(const short8*)&As[buf][(rw0 + 64 + i * 16 + (lane & 15)) * 32 + rchunk];
    if (t + 2 < NT) {
      stageB(sbuf, kf, 0); stageB(sbuf, kf, 1);
      asm volatile("s_waitcnt vmcnt(4)" ::: "memory");   // tile t+1 certified
    } else if (t + 1 < NT) {
      asm volatile("s_waitcnt vmcnt(0)" ::: "memory");
    }
    __builtin_amdgcn_s_barrier();
    __builtin_amdgcn_s_setprio(1);
#pragma unroll
    for (int i = 0; i < 4; ++i)
#pragma unroll
      for (int j = 0; j < 4; ++j)
        acc[4 + i][j] = __builtin_amdgcn_mfma_f32_16x16x32_bf16(a1[i], b0[j], acc[4 + i][j], 0, 0, 0);
    __builtin_amdgcn_s_setprio(0);
    __builtin_amdgcn_s_barrier();
    buf = (buf == 2) ? 0 : buf + 1;
  }

  // ---- epilogue (EPI=2): u / silu(z), bwd rows reversed ----
#pragma unroll
  for (int i = 0; i < 8; ++i)
#pragma unroll
    for (int r = 0; r < 4; ++r) {
      int m = bm + rw0 + i * 16 + (lane >> 4) * 4 + r;
#pragma unroll
      for (int j = 0; j < 4; ++j) {
        int n = bn + cw0 + j * 16 + (lane & 15);
        float v = acc[i][j][r];
        int dir = n >> 11;
        int nn = n & 2047;
        int sub = nn & 1023;
        int row = dir ? revrow(m) : m;
        if (nn < D_INNER)
          Cu[dir * USLAB + (long)row * 1024 + sub] = f2b(v);
        else
          Cz[dir * USLAB + (long)row * 1024 + sub] = f2b(v * sigmoidf_(v));
      }
    }
}

// ---------------- bf16 MFMA GEMM: 2-phase dbuf + T2 swizzle + T1 -----------
// (kept for x_proj / dt_proj / out_proj)
template<int BM, int BN, int RW, int CW, int EPI, int DUALK, int MDIAG>
__global__ __launch_bounds__(256) void gemm_bf16(
    const ushort* __restrict__ A, int lda, const ushort* __restrict__ A2,
    const ushort* __restrict__ B, int ldb, const ushort* __restrict__ B2,
    float* __restrict__ Cf, ushort* __restrict__ Cb, ushort* __restrict__ Cb2,
    int ldc, int K, const float* __restrict__ bias, const float* __restrict__ bias2,
    int b_stride, int revC, int accumC)
{
  constexpr int MI = BM / RW / 16;
  constexpr int NJ = BN / CW / 16;
  __shared__ ushort As[2][BM * 32];
  __shared__ ushort Bs[2][BN * 32];
  const int tid = threadIdx.x;
  const int w = tid >> 6, lane = tid & 63;

  const int nwg = gridDim.x * gridDim.y;
  int bid = blockIdx.y * gridDim.x + blockIdx.x;
  int wgid = (bid & 7) * (nwg >> 3) + (bid >> 3);
  const int bm = (wgid / gridDim.x) * BM;
  const int bn = (wgid % gridDim.x) * BN;

  if (MDIAG) {
    int mdir = (bm >= NROWS) ? 1 : 0;
    B += mdir * b_stride;
    if (mdir) bias = bias2;
  }

  const int rw0 = (w / CW) * (MI * 16);
  const int cw0 = (w % CW) * (NJ * 16);
  const int srow = w * 16 + (lane >> 2);
  const int scol = (((lane & 3) ^ ((lane >> 3) & 3)) << 3);
  const int rchunk = (((lane >> 4) ^ (((lane & 15) >> 1) & 3)) << 3);

  f32x4 acc[MI][NJ] = {};

  auto stage = [&](int buf, int k0) {
    const ushort* Ap = A;
    const ushort* Bp = B;
    int kc = k0;
    bool hi = false;
    if (DUALK && k0 >= (K >> 1)) { Ap = A2; Bp = B2; kc = k0 - (K >> 1); hi = true; }
#pragma unroll
    for (int it = 0; it < BM / 64; ++it) {
      int gm = bm + it * 64 + srow;
      int arow = (DUALK && hi) ? revrow(gm) : gm;
      gload16(Ap + (long)arow * lda + kc + scol, &As[buf][(it * 64 + w * 16) * 32]);
    }
#pragma unroll
    for (int it = 0; it < BN / 64; ++it) {
      int gn = bn + it * 64 + srow;
      gload16(Bp + (long)gn * ldb + kc + scol, &Bs[buf][(it * 64 + w * 16) * 32]);
    }
  };

  stage(0, 0);
  __syncthreads();

  for (int k0 = 0; k0 < K; k0 += 32) {
    int cur = (k0 >> 5) & 1;
    if (k0 + 32 < K) stage(cur ^ 1, k0 + 32);
    short8 a[MI], b[NJ];
#pragma unroll
    for (int i = 0; i < MI; ++i)
      a[i] = *(const short8*)&As[cur][(rw0 + i * 16 + (lane & 15)) * 32 + rchunk];
#pragma unroll
    for (int j = 0; j < NJ; ++j)
      b[j] = *(const short8*)&Bs[cur][(cw0 + j * 16 + (lane & 15)) * 32 + rchunk];
#pragma unroll
    for (int i = 0; i < MI; ++i)
#pragma unroll
      for (int j = 0; j < NJ; ++j)
        acc[i][j] = __builtin_amdgcn_mfma_f32_16x16x32_bf16(a[i], b[j], acc[i][j], 0, 0, 0);
    __syncthreads();
  }

#pragma unroll
  for (int i = 0; i < MI; ++i)
#pragma unroll
    for (int r = 0; r < 4; ++r) {
      int m = bm + rw0 + i * 16 + (lane >> 4) * 4 + r;
      int crow = revC ? revrow(m) : m;
#pragma unroll
      for (int j = 0; j < NJ; ++j) {
        int n = bn + cw0 + j * 16 + (lane & 15);
        float v = acc[i][j][r];
        if (EPI == 0) {
          float* p = Cf + (long)crow * ldc + n;
          if (accumC) *p += v; else *p = v;
        } else if (EPI == 1) {
          Cb[(long)crow * ldc + n] = f2b(softplus_(v + bias[n]));
        } else if (EPI == 2) {
          int dir = n >> 11;
          int nn = n & 2047;
          int sub = nn & 1023;
          int row = dir ? revrow(m) : m;
          if (nn < D_INNER)
            Cb[dir * USLAB + (long)row * 1024 + sub] = f2b(v);
          else
            Cb2[dir * USLAB + (long)row * 1024 + sub] = f2b(v * sigmoidf_(v));
        } else {  // EPI == 4
          Cb[(long)crow * ldc + n] = f2b(v);
        }
      }
    }
}

// ---------------- fused fp32->bf16 converter (x + 8 weight tensors) --------
struct Seg { const float4* s; ushort4* d; int n4; int bstart; };
struct ConvArgs { Seg seg[9]; };

__global__ __launch_bounds__(256) void convert_all(ConvArgs a)
{
  int blk = blockIdx.x;
  int i = 0;
#pragma unroll
  for (int k = 1; k < 9; ++k) if (blk >= a.seg[k].bstart) i = k;
  int idx = (blk - a.seg[i].bstart) * 256 + threadIdx.x;
  if (idx >= a.seg[i].n4) return;
  float4 v = a.seg[i].s[idx];
  ushort4 o;
  o.x = f2b(v.x); o.y = f2b(v.y); o.z = f2b(v.z); o.w = f2b(v.w);
  a.seg[i].d[idx] = o;
}

// ------------- conv1d(k=4) + bias + silu, both dirs (4 d/thread) -----------
__global__ __launch_bounds__(256) void conv_silu(
    const ushort* __restrict__ u_bf,   // [2][8192][1024]
    const float* __restrict__ cw_f, const float* __restrict__ cw_b,
    const float* __restrict__ cb_f, const float* __restrict__ cb_b,
    ushort* __restrict__ uc_bf)        // [2][8192][1024]
{
  long i = (long)blockIdx.x * 256 + threadIdx.x;
  int dir = (int)(i >> 21);
  int r = (int)(i >> 8) & 8191;
  int d0 = ((int)i & 255) << 2;
  int t = r & (SEQ - 1);
  const float* cw = dir ? cw_b : cw_f;
  const float* cb = dir ? cb_b : cb_f;
  const ushort* p = u_bf + dir * USLAB + (long)r * D_INNER + d0;
  ushort4 u0 = *(const ushort4*)p;
  ushort4 u1 = (t >= 1) ? *(const ushort4*)(p - 1024) : ushort4{0, 0, 0, 0};
  ushort4 u2 = (t >= 2) ? *(const ushort4*)(p - 2048) : ushort4{0, 0, 0, 0};
  ushort4 u3 = (t >= 3) ? *(const ushort4*)(p - 3072) : ushort4{0, 0, 0, 0};
  float4 bb = *(const float4*)(cb + d0);
  float ub0[4] = {b2f(u0.x), b2f(u0.y), b2f(u0.z), b2f(u0.w)};
  float ub1[4] = {b2f(u1.x), b2f(u1.y), b2f(u1.z), b2f(u1.w)};
  float ub2[4] = {b2f(u2.x), b2f(u2.y), b2f(u2.z), b2f(u2.w)};
  float ub3[4] = {b2f(u3.x), b2f(u3.y), b2f(u3.z), b2f(u3.w)};
  float bbv[4] = {bb.x, bb.y, bb.z, bb.w};
  ushort ov[4];
#pragma unroll
  for (int j = 0; j < 4; ++j) {
    float4 wj = *(const float4*)(cw + (d0 + j) * 4);
    float acc = bbv[j];
    acc = fmaf(wj.w, ub0[j], acc);
    acc = fmaf(wj.z, ub1[j], acc);
    acc = fmaf(wj.y, ub2[j], acc);
    acc = fmaf(wj.x, ub3[j], acc);
    ov[j] = f2b(acc * sigmoidf_(acc));
  }
  ushort4 o;
  o.x = ov[0]; o.y = ov[1]; o.z = ov[2]; o.w = ov[3];
  *(ushort4*)(uc_bf + dir * USLAB + (long)r * D_INNER + d0) = o;
}

// Decay powers E^(s+1), s=0..15, from E = exp(-dt).
#define EP_FAST(dt, Ep)                                        \
  {                                                            \
    float E1 = __expf(-(dt));                                  \
    float E2 = E1 * E1, E4 = E2 * E2, E8 = E4 * E4;            \
    Ep[0] = E1;  Ep[1] = E2;      Ep[2] = E2 * E1;             \
    Ep[3] = E4;  Ep[4] = E4 * E1; Ep[5] = E4 * E2;             \
    Ep[6] = E4 * Ep[2]; Ep[7] = E8;  Ep[8] = E8 * E1;          \
    Ep[9] = E8 * E2; Ep[10] = E8 * Ep[2]; Ep[11] = E8 * E4;    \
    Ep[12] = E8 * Ep[4]; Ep[13] = E8 * Ep[5];                  \
    Ep[14] = E8 * Ep[6]; Ep[15] = E8 * E8;                     \
  }

__device__ __forceinline__ bool a_is_arange(const float* Ar) {
  bool ok = true;
#pragma unroll
  for (int s = 0; s < D_STATE; ++s)
    ok = ok && (fabsf(Ar[s] + (float)(s + 1)) <= 1e-3f * (float)(s + 1));
  return ok;
}

// ---------------- chunked selective scan (both dirs in one grid) -----------
// idx bits: d[0:10) c[10:16) b[16:19) dir[19]
__global__ __launch_bounds__(256) void scan_partA(
    const ushort* __restrict__ delta_bf,
    const ushort* __restrict__ ucv_bf,
    const ushort* __restrict__ dblb,
    const float* __restrict__ A_log_f, const float* __restrict__ A_log_b,
    ushort* __restrict__ hend,            // [2][8][CH][16][1024] bf16
    float* __restrict__ dtsum_buf)        // [2][8][CH][1024]
{
  __shared__ float bc[CL][16];
  long idx = (long)blockIdx.x * 256 + threadIdx.x;
  int d = (int)idx & 1023;
  int c = ((int)idx >> 10) & (CH - 1);
  int b = ((int)idx >> 16) & 7;
  int dir = (int)(idx >> 19);
  const long r0 = (long)b * SEQ + c * CL;
  const ushort* dblp = dblb + (long)dir * NROWS * 64;
  {
    int tt = threadIdx.x >> 4, ss = threadIdx.x & 15;
    bc[tt][ss] = b2f(dblp[(r0 + tt) * 64 + 32 + ss]);
  }
  const float* Alog = dir ? A_log_b : A_log_f;
  const ushort* dp = delta_bf + dir * USLAB;
  const ushort* up = ucv_bf + dir * USLAB;
  float Ar[D_STATE];
#pragma unroll
  for (int s = 0; s < D_STATE; ++s) Ar[s] = -__expf(Alog[d * D_STATE + s]);
  const bool fast = a_is_arange(Ar);
  float h[D_STATE] = {0.f};
  float dtsum = 0.f;
  __syncthreads();

  if (fast) {
    for (int t = 0; t < CL; ++t) {
      long r = r0 + t;
      float dt = b2f(dp[r * 1024 + d]);
      float u  = b2f(up[r * 1024 + d]);
      float du = dt * u;
      dtsum += dt;
      float Ep[16];
      EP_FAST(dt, Ep);
#pragma unroll
      for (int s = 0; s < D_STATE; ++s)
        h[s] = fmaf(h[s], Ep[s], du * bc[t][s]);
    }
  } else {
    for (int t = 0; t < CL; ++t) {
      long r = r0 + t;
      float dt = b2f(dp[r * 1024 + d]);
      float u  = b2f(up[r * 1024 + d]);
      float du = dt * u;
      dtsum += dt;
#pragma unroll
      for (int s = 0; s < D_STATE; ++s)
        h[s] = fmaf(h[s], __expf(dt * Ar[s]), du * bc[t][s]);
    }
  }
  long base = ((long)((dir * 8 + b) * CH + c) * D_STATE) * 1024 + d;
#pragma unroll
  for (int s = 0; s < D_STATE; ++s) hend[base + s * 1024] = f2b(h[s]);
  dtsum_buf[(long)((dir * 8 + b) * CH + c) * 1024 + d] = dtsum;
}

// idx bits: d[0:10) s[10:14) b[14:17) dir[17]
__global__ __launch_bounds__(256) void scan_partB(
    ushort* __restrict__ hend,
    const float* __restrict__ dtsum_buf,
    const float* __restrict__ A_log_f, const float* __restrict__ A_log_b)
{
  long idx = (long)blockIdx.x * 256 + threadIdx.x;
  int d = (int)idx & 1023;
  int s = ((int)idx >> 10) & 15;
  int b = ((int)idx >> 14) & 7;
  int dir = (int)(idx >> 17);
  const float* Alog = dir ? A_log_b : A_log_f;
  float Ars = -__expf(Alog[d * D_STATE + s]);
  float H = 0.f;
  for (int c = 0; c < CH; ++c) {
    long off = ((long)((dir * 8 + b) * CH + c) * D_STATE + s) * 1024 + d;
    float he = b2f(hend[off]);
    float P = __expf(Ars * dtsum_buf[(long)((dir * 8 + b) * CH + c) * 1024 + d]);
    hend[off] = f2b(H);
    H = fmaf(P, H, he);
  }
}

__global__ __launch_bounds__(256) void scan_partC(
    const ushort* __restrict__ delta_bf,
    const ushort* __restrict__ ucv_bf,
    const ushort* __restrict__ dblb,
    const float* __restrict__ A_log_f, const float* __restrict__ A_log_b,
    const float* __restrict__ Dp_f, const float* __restrict__ Dp_b,
    const ushort* __restrict__ zsilu_bf,
    const ushort* __restrict__ hinit,
    ushort* __restrict__ ydz_bf)          // elementwise alias of ucv_bf
{
  __shared__ float bc[CL][32];
  long idx = (long)blockIdx.x * 256 + threadIdx.x;
  int d = (int)idx & 1023;
  int c = ((int)idx >> 10) & (CH - 1);
  int b = ((int)idx >> 16) & 7;
  int dir = (int)(idx >> 19);
  const long r0 = (long)b * SEQ + c * CL;
  const ushort* dblp = dblb + (long)dir * NROWS * 64;
  {
    int tt = threadIdx.x >> 4, cc = (threadIdx.x & 15) * 2;
    ushort2 v = *(const ushort2*)&dblp[(r0 + tt) * 64 + 32 + cc];
    bc[tt][cc] = b2f(v.x); bc[tt][cc + 1] = b2f(v.y);
  }
  const float* Alog = dir ? A_log_b : A_log_f;
  const ushort* dp = delta_bf + dir * USLAB;
  const ushort* up = ucv_bf + dir * USLAB;
  const ushort* zp = zsilu_bf + dir * USLAB;
  ushort* yp = ydz_bf + dir * USLAB;
  float Ar[D_STATE];
#pragma unroll
  for (int s = 0; s < D_STATE; ++s) Ar[s] = -__expf(Alog[d * D_STATE + s]);
  const bool fast = a_is_arange(Ar);
  float h[D_STATE];
  long base = ((long)((dir * 8 + b) * CH + c) * D_STATE) * 1024 + d;
#pragma unroll
  for (int s = 0; s < D_STATE; ++s) h[s] = b2f(hinit[base + s * 1024]);
  float Dd = (dir ? Dp_b : Dp_f)[d];
  __syncthreads();

  if (fast) {
    for (int t = 0; t < CL; ++t) {
      long r = r0 + t;
      float dt = b2f(dp[r * 1024 + d]);
      float u  = b2f(up[r * 1024 + d]);
      float du = dt * u;
      float Ep[16];
      EP_FAST(dt, Ep);
      float y = 0.f;
#pragma unroll
      for (int s = 0; s < D_STATE; ++s) {
        h[s] = fmaf(h[s], Ep[s], du * bc[t][s]);
        y = fmaf(h[s], bc[t][16 + s], y);
      }
      float zs = b2f(zp[r * 1024 + d]);
      float yv = fmaf(u, Dd, y);
      yp[r * 1024 + d] = f2b(yv * zs);
    }
  } else {
    for (int t = 0; t < CL; ++t) {
      long r = r0 + t;
      float dt = b2f(dp[r * 1024 + d]);
      float u  = b2f(up[r * 1024 + d]);
      float du = dt * u;
      float y = 0.f;
#pragma unroll
      for (int s = 0; s < D_STATE; ++s) {
        h[s] = fmaf(h[s], __expf(dt * Ar[s]), du * bc[t][s]);
        y = fmaf(h[s], bc[t][16 + s], y);
      }
      float zs = b2f(zp[r * 1024 + d]);
      float yv = fmaf(u, Dd, y);
      yp[r * 1024 + d] = f2b(yv * zs);
    }
  }
}

extern "C" void kernel_launch(void* const* d_in, const int* in_sizes, int n_in,
                              void* d_out, int out_size, void* d_ws, size_t ws_size,
                              hipStream_t stream)
{
  const float* x = (const float*)d_in[0];
  float* out = (float*)d_out;
  char* ws = (char*)d_ws;
  // Layout (MiB offsets), total 136 MiB:
  ushort* zsilu  = (ushort*)(ws);                     // 32: [2][8192][1024]
  ushort* ucv    = (ushort*)(ws + (32ul << 20));      // 32: [2][8192][1024] (=ydz)
  ushort* u_bf   = (ushort*)(ws + (64ul << 20));      // 32: [2][8192][1024] (=delta)
  ushort* hend   = (ushort*)(ws + (96ul << 20));      // 32: [2][8][CH][16][1024] bf16
  float*  dtsum  = (float*)(ws + (128ul << 20));      //  4: [2][8][CH][1024]
  ushort* dblb   = (ushort*)(ws + (132ul << 20));     //  2: [2][8192][64]
  ushort* out_wb = (ushort*)(ws + (134ul << 20));     //  2: [2][512][1024]
  // transient aliases inside hend slab (dead before scan_partA writes hend):
  ushort* xbf    = hend;                              //  8: [8192][512]
  ushort* in_wb  = hend + (8ul << 19);                //  4: [4096][512]
  ushort* xp_wb  = hend + (12ul << 19);
  ushort* dt_wb  = xp_wb + 131072;
  ushort* delta  = u_bf;
  ushort* ydz    = ucv;

  ConvArgs ca;
  int bcur = 0, si = 0;
  auto addseg = [&](const float* s, ushort* d, int nelem) {
    ca.seg[si].s = (const float4*)s; ca.seg[si].d = (ushort4*)d;
    ca.seg[si].n4 = nelem / 4; ca.seg[si].bstart = bcur;
    bcur += (nelem / 4 + 255) / 256; ++si;
  };
  addseg(x, xbf, NROWS * D_MODEL);
  addseg((const float*)d_in[1], in_wb, 2048 * 512);           // in_w_f
  addseg((const float*)d_in[10], in_wb + 2048 * 512, 2048 * 512); // in_w_b
  addseg((const float*)d_in[9], out_wb, 512 * 1024);          // out_w_f
  addseg((const float*)d_in[18], out_wb + 512 * 1024, 512 * 1024);
  addseg((const float*)d_in[4], xp_wb, 64 * 1024);            // xp_w_f
  addseg((const float*)d_in[13], xp_wb + 65536, 64 * 1024);
  addseg((const float*)d_in[5], dt_wb, 1024 * 32);            // dt_w_f
  addseg((const float*)d_in[14], dt_wb + 32768, 1024 * 32);

  dim3 blk(256);
  convert_all<<<dim3(bcur), blk, 0, stream>>>(ca);

  // 1) merged in_proj via 256x256 counted-vmcnt pipeline (512 threads)
  inproj256<<<dim3(4096 / 256, NROWS / 256), dim3(512), 0, stream>>>(
      xbf, D_MODEL, in_wb, D_MODEL, u_bf, zsilu, D_MODEL);
  // 2) conv + silu, both dirs
  conv_silu<<<dim3(2 * NROWS), blk, 0, stream>>>(
      u_bf, (const float*)d_in[2], (const float*)d_in[11],
      (const float*)d_in[3], (const float*)d_in[12], ucv);
  // 3) x_proj, both dirs in one block-diag dispatch: M=16384, BM=64
  gemm_bf16<64, 64, 2, 2, 4, 0, 1><<<dim3(1, 256), blk, 0, stream>>>(
      ucv, D_INNER, nullptr, xp_wb, D_INNER, nullptr,
      nullptr, dblb, nullptr, 64, D_INNER, nullptr, nullptr, 65536, 0, 0);
  // 4) dt_proj + softplus, both dirs block-diag: M=16384, K=32
  gemm_bf16<128, 128, 2, 2, 1, 0, 1><<<dim3(8, 128), blk, 0, stream>>>(
      dblb, 64, nullptr, dt_wb, DT_RANK, nullptr,
      nullptr, delta, nullptr, D_INNER, DT_RANK,
      (const float*)d_in[6], (const float*)d_in[15], 32768, 0, 0);
  // 5) chunked scan, both dirs
  const float* Alf = (const float*)d_in[7];
  const float* Alb = (const float*)d_in[16];
  scan_partA<<<dim3(2 * BATCH * CH * 1024 / 256), blk, 0, stream>>>(
      delta, ucv, dblb, Alf, Alb, hend, dtsum);
  scan_partB<<<dim3(2 * BATCH * 16 * 1024 / 256), blk, 0, stream>>>(
      hend, dtsum, Alf, Alb);
  scan_partC<<<dim3(2 * BATCH * CH * 1024 / 256), blk, 0, stream>>>(
      delta, ucv, dblb, Alf, Alb,
      (const float*)d_in[8], (const float*)d_in[17], zsilu, hend, ydz);
  // 6) out_proj, both dirs in one K=2048 dispatch (bwd half: reversed rows)
  gemm_bf16<128, 128, 2, 2, 0, 1, 0><<<dim3(4, 64), blk, 0, stream>>>(
      ydz, D_INNER, ydz + USLAB, out_wb, D_INNER, out_wb + 512 * 1024,
      out, nullptr, nullptr, D_MODEL, 2 * D_INNER, nullptr, nullptr, 0, 0, 0);
}

// Round 12
// 252.201 us; speedup vs baseline: 1.0287x; 1.0287x over previous
//
#include <hip/hip_runtime.h>
#include <math.h>

#define BATCH 8
#define SEQ 1024
#define D_MODEL 512
#define D_INNER 1024
#define D_STATE 16
#define DT_RANK 32
#define NROWS (BATCH * SEQ)   // 8192
#define CH 64                 // chunks per sequence
#define CL 16                 // chunk length
#define USLAB 8388608l        // 8192*1024 elems (one dir slab)

typedef short short8 __attribute__((ext_vector_type(8)));
typedef float f32x4 __attribute__((ext_vector_type(4)));

__device__ __forceinline__ float sigmoidf_(float x) { return 1.f / (1.f + __expf(-x)); }

__device__ __forceinline__ float softplus_(float v) {
  return (v > 20.f) ? v : __logf(1.f + __expf(v));
}

__device__ __forceinline__ ushort f2b(float f) {  // fp32 -> bf16 RNE
  uint u = __float_as_uint(f);
  return (ushort)((u + 0x7FFFu + ((u >> 16) & 1u)) >> 16);
}
__device__ __forceinline__ float b2f(ushort u) {
  return __uint_as_float(((uint)u) << 16);
}

__device__ __forceinline__ void gload16(const ushort* g, const ushort* l) {
  __builtin_amdgcn_global_load_lds(
      (const __attribute__((address_space(1))) void*)g,
      (__attribute__((address_space(3))) void*)l, 16, 0, 0);
}

__device__ __forceinline__ int revrow(int m) {
  return (m & ~1023) | (1023 - (m & 1023));
}

// ========== in_proj: 256x256 tile, 8 waves, counted-vmcnt pipeline =========
// Epilogue: per-wave LDS transpose -> full-line dwordx4 stores (R12 theory:
// scattered 2B stores cap GEMMs at ~1.4 TB/s of output).
__global__ __launch_bounds__(512, 2) void inproj256(
    const ushort* __restrict__ A, int lda,      // [8192][512]
    const ushort* __restrict__ B, int ldb,      // [4096][512]
    ushort* __restrict__ Cu, ushort* __restrict__ Cz,
    int K)
{
  __shared__ ushort As[3][256 * 32];
  __shared__ ushort Bs[3][256 * 32];
  const int tid = threadIdx.x;
  const int w = tid >> 6, lane = tid & 63;

  const int nwg = gridDim.x * gridDim.y;        // %8 == 0
  int bid = blockIdx.y * gridDim.x + blockIdx.x;
  int wgid = (bid & 7) * (nwg >> 3) + (bid >> 3);
  const int bm = (wgid / gridDim.x) * 256;
  const int bn = (wgid % gridDim.x) * 256;

  const int wr = w >> 2, wc = w & 3;            // 2x4 wave grid
  const int rw0 = wr * 128, cw0 = wc * 64;      // per-wave 128x64 output
  const int srow = w * 16 + (lane >> 2);
  const int scol = (((lane & 3) ^ ((lane >> 3) & 3)) << 3);
  const int rchunk = (((lane >> 4) ^ (((lane & 15) >> 1) & 3)) << 3);

  f32x4 acc[8][4] = {};

  auto stageA = [&](int buf, int k0, int half) {
    int gm = bm + half * 128 + srow;
    gload16(A + (long)gm * lda + k0 + scol, &As[buf][(half * 128 + w * 16) * 32]);
  };
  auto stageB = [&](int buf, int k0, int half) {
    int gn = bn + half * 128 + srow;
    gload16(B + (long)gn * ldb + k0 + scol, &Bs[buf][(half * 128 + w * 16) * 32]);
  };

  const int NT = K >> 5;                         // 16 for K=512
  stageA(0, 0, 0); stageA(0, 0, 1); stageB(0, 0, 0); stageB(0, 0, 1);
  stageA(1, 32, 0); stageA(1, 32, 1); stageB(1, 32, 0); stageB(1, 32, 1);
  asm volatile("s_waitcnt vmcnt(4)" ::: "memory");
  __builtin_amdgcn_s_barrier();

  int buf = 0;
  for (int t = 0; t < NT; ++t) {
    const int kf = (t + 2) << 5;
    const int sbuf = (buf >= 1) ? buf - 1 : buf + 2;
    short8 a0[4], b0[4];
#pragma unroll
    for (int i = 0; i < 4; ++i)
      a0[i] = *(const short8*)&As[buf][(rw0 + i * 16 + (lane & 15)) * 32 + rchunk];
#pragma unroll
    for (int j = 0; j < 4; ++j)
      b0[j] = *(const short8*)&Bs[buf][(cw0 + j * 16 + (lane & 15)) * 32 + rchunk];
    if (t + 2 < NT) { stageA(sbuf, kf, 0); stageA(sbuf, kf, 1); }
    __builtin_amdgcn_s_barrier();
    __builtin_amdgcn_s_setprio(1);
#pragma unroll
    for (int i = 0; i < 4; ++i)
#pragma unroll
      for (int j = 0; j < 4; ++j)
        acc[i][j] = __builtin_amdgcn_mfma_f32_16x16x32_bf16(a0[i], b0[j], acc[i][j], 0, 0, 0);
    __builtin_amdgcn_s_setprio(0);
    __builtin_amdgcn_s_barrier();
    short8 a1[4];
#pragma unroll
    for (int i = 0; i < 4; ++i)
      a1[i] = *(const short8*)&As[buf][(rw0 + 64 + i * 16 + (lane & 15)) * 32 + rchunk];
    if (t + 2 < NT) {
      stageB(sbuf, kf, 0); stageB(sbuf, kf, 1);
      asm volatile("s_waitcnt vmcnt(4)" ::: "memory");
    } else if (t + 1 < NT) {
      asm volatile("s_waitcnt vmcnt(0)" ::: "memory");
    }
    __builtin_amdgcn_s_barrier();
    __builtin_amdgcn_s_setprio(1);
#pragma unroll
    for (int i = 0; i < 4; ++i)
#pragma unroll
      for (int j = 0; j < 4; ++j)
        acc[4 + i][j] = __builtin_amdgcn_mfma_f32_16x16x32_bf16(a1[i], b0[j], acc[4 + i][j], 0, 0, 0);
    __builtin_amdgcn_s_setprio(0);
    __builtin_amdgcn_s_barrier();
    buf = (buf == 2) ? 0 : buf + 1;
  }

  // ---- epilogue: per-wave LDS transpose, full-line stores ----
  // block-uniform flags: BN=256 never straddles the 1024 (u/z) or 2048 (dir)
  // boundaries.
  const int bdir = bn >> 11;
  const int bz = ((bn & 2047) >= 1024);
  const int bncol = bn & 1023;
  ushort* Cp = (bz ? Cz : Cu) + (long)bdir * USLAB;
  ushort* scr = &As[0][0] + w * 1024;            // 16x64 ushort per wave

#pragma unroll
  for (int i = 0; i < 8; ++i) {
#pragma unroll
    for (int r = 0; r < 4; ++r)
#pragma unroll
      for (int j = 0; j < 4; ++j) {
        float v = acc[i][j][r];
        if (bz) v = v * sigmoidf_(v);
        scr[((lane >> 4) * 4 + r) * 64 + j * 16 + (lane & 15)] = f2b(v);
      }
#pragma unroll
    for (int q = 0; q < 2; ++q) {
      int r16 = (lane >> 3) + q * 8;             // 0..15
      short8 pk = *(const short8*)&scr[r16 * 64 + (lane & 7) * 8];
      int m = bm + rw0 + i * 16 + r16;
      int row = bdir ? revrow(m) : m;
      *(short8*)&Cp[(long)row * 1024 + bncol + cw0 + (lane & 7) * 8] = pk;
    }
  }
}

// ---------------- bf16 MFMA GEMM: 2-phase dbuf + T2 swizzle + T1 -----------
// EPI: 0 = fp32 store, 1 = softplus->bf16 (LDS-transposed stores), 4 = bf16
template<int BM, int BN, int RW, int CW, int EPI, int DUALK, int MDIAG>
__global__ __launch_bounds__(256) void gemm_bf16(
    const ushort* __restrict__ A, int lda, const ushort* __restrict__ A2,
    const ushort* __restrict__ B, int ldb, const ushort* __restrict__ B2,
    float* __restrict__ Cf, ushort* __restrict__ Cb, ushort* __restrict__ Cb2,
    int ldc, int K, const float* __restrict__ bias, const float* __restrict__ bias2,
    int b_stride, int revC, int accumC)
{
  constexpr int MI = BM / RW / 16;
  constexpr int NJ = BN / CW / 16;
  __shared__ ushort As[2][BM * 32];
  __shared__ ushort Bs[2][BN * 32];
  const int tid = threadIdx.x;
  const int w = tid >> 6, lane = tid & 63;

  const int nwg = gridDim.x * gridDim.y;
  int bid = blockIdx.y * gridDim.x + blockIdx.x;
  int wgid = (bid & 7) * (nwg >> 3) + (bid >> 3);
  const int bm = (wgid / gridDim.x) * BM;
  const int bn = (wgid % gridDim.x) * BN;

  if (MDIAG) {
    int mdir = (bm >= NROWS) ? 1 : 0;
    B += mdir * b_stride;
    if (mdir) bias = bias2;
  }

  const int rw0 = (w / CW) * (MI * 16);
  const int cw0 = (w % CW) * (NJ * 16);
  const int srow = w * 16 + (lane >> 2);
  const int scol = (((lane & 3) ^ ((lane >> 3) & 3)) << 3);
  const int rchunk = (((lane >> 4) ^ (((lane & 15) >> 1) & 3)) << 3);

  f32x4 acc[MI][NJ] = {};

  auto stage = [&](int buf, int k0) {
    const ushort* Ap = A;
    const ushort* Bp = B;
    int kc = k0;
    bool hi = false;
    if (DUALK && k0 >= (K >> 1)) { Ap = A2; Bp = B2; kc = k0 - (K >> 1); hi = true; }
#pragma unroll
    for (int it = 0; it < BM / 64; ++it) {
      int gm = bm + it * 64 + srow;
      int arow = (DUALK && hi) ? revrow(gm) : gm;
      gload16(Ap + (long)arow * lda + kc + scol, &As[buf][(it * 64 + w * 16) * 32]);
    }
#pragma unroll
    for (int it = 0; it < BN / 64; ++it) {
      int gn = bn + it * 64 + srow;
      gload16(Bp + (long)gn * ldb + kc + scol, &Bs[buf][(it * 64 + w * 16) * 32]);
    }
  };

  stage(0, 0);
  __syncthreads();

  for (int k0 = 0; k0 < K; k0 += 32) {
    int cur = (k0 >> 5) & 1;
    if (k0 + 32 < K) stage(cur ^ 1, k0 + 32);
    short8 a[MI], b[NJ];
#pragma unroll
    for (int i = 0; i < MI; ++i)
      a[i] = *(const short8*)&As[cur][(rw0 + i * 16 + (lane & 15)) * 32 + rchunk];
#pragma unroll
    for (int j = 0; j < NJ; ++j)
      b[j] = *(const short8*)&Bs[cur][(cw0 + j * 16 + (lane & 15)) * 32 + rchunk];
#pragma unroll
    for (int i = 0; i < MI; ++i)
#pragma unroll
      for (int j = 0; j < NJ; ++j)
        acc[i][j] = __builtin_amdgcn_mfma_f32_16x16x32_bf16(a[i], b[j], acc[i][j], 0, 0, 0);
    __syncthreads();
  }

  if (EPI == 1) {
    // LDS-transposed bf16 stores (full 128B lines); NJ*16 == 64 cols/wave
    ushort* scr = &As[0][0] + w * 1024;
#pragma unroll
    for (int i = 0; i < MI; ++i) {
#pragma unroll
      for (int r = 0; r < 4; ++r)
#pragma unroll
        for (int j = 0; j < NJ; ++j) {
          int n = bn + cw0 + j * 16 + (lane & 15);
          float v = softplus_(acc[i][j][r] + bias[n]);
          scr[((lane >> 4) * 4 + r) * 64 + j * 16 + (lane & 15)] = f2b(v);
        }
#pragma unroll
      for (int q = 0; q < 2; ++q) {
        int r16 = (lane >> 3) + q * 8;
        short8 pk = *(const short8*)&scr[r16 * 64 + (lane & 7) * 8];
        int m = bm + rw0 + i * 16 + r16;
        *(short8*)&Cb[(long)m * ldc + bn + cw0 + (lane & 7) * 8] = pk;
      }
    }
  } else {
#pragma unroll
    for (int i = 0; i < MI; ++i)
#pragma unroll
      for (int r = 0; r < 4; ++r) {
        int m = bm + rw0 + i * 16 + (lane >> 4) * 4 + r;
        int crow = revC ? revrow(m) : m;
#pragma unroll
        for (int j = 0; j < NJ; ++j) {
          int n = bn + cw0 + j * 16 + (lane & 15);
          float v = acc[i][j][r];
          if (EPI == 0) {
            float* p = Cf + (long)crow * ldc + n;
            if (accumC) *p += v; else *p = v;
          } else {  // EPI == 4
            Cb[(long)crow * ldc + n] = f2b(v);
          }
        }
      }
  }
}

// ---------------- fused fp32->bf16 converter (x + 8 weight tensors) --------
struct Seg { const float4* s; ushort4* d; int n4; int bstart; };
struct ConvArgs { Seg seg[9]; };

__global__ __launch_bounds__(256) void convert_all(ConvArgs a)
{
  int blk = blockIdx.x;
  int i = 0;
#pragma unroll
  for (int k = 1; k < 9; ++k) if (blk >= a.seg[k].bstart) i = k;
  int idx = (blk - a.seg[i].bstart) * 256 + threadIdx.x;
  if (idx >= a.seg[i].n4) return;
  float4 v = a.seg[i].s[idx];
  ushort4 o;
  o.x = f2b(v.x); o.y = f2b(v.y); o.z = f2b(v.z); o.w = f2b(v.w);
  a.seg[i].d[idx] = o;
}

// ------------- conv1d(k=4) + bias + silu, both dirs (4 d/thread) -----------
__global__ __launch_bounds__(256) void conv_silu(
    const ushort* __restrict__ u_bf,
    const float* __restrict__ cw_f, const float* __restrict__ cw_b,
    const float* __restrict__ cb_f, const float* __restrict__ cb_b,
    ushort* __restrict__ uc_bf)
{
  long i = (long)blockIdx.x * 256 + threadIdx.x;
  int dir = (int)(i >> 21);
  int r = (int)(i >> 8) & 8191;
  int d0 = ((int)i & 255) << 2;
  int t = r & (SEQ - 1);
  const float* cw = dir ? cw_b : cw_f;
  const float* cb = dir ? cb_b : cb_f;
  const ushort* p = u_bf + dir * USLAB + (long)r * D_INNER + d0;
  ushort4 u0 = *(const ushort4*)p;
  ushort4 u1 = (t >= 1) ? *(const ushort4*)(p - 1024) : ushort4{0, 0, 0, 0};
  ushort4 u2 = (t >= 2) ? *(const ushort4*)(p - 2048) : ushort4{0, 0, 0, 0};
  ushort4 u3 = (t >= 3) ? *(const ushort4*)(p - 3072) : ushort4{0, 0, 0, 0};
  float4 bb = *(const float4*)(cb + d0);
  float ub0[4] = {b2f(u0.x), b2f(u0.y), b2f(u0.z), b2f(u0.w)};
  float ub1[4] = {b2f(u1.x), b2f(u1.y), b2f(u1.z), b2f(u1.w)};
  float ub2[4] = {b2f(u2.x), b2f(u2.y), b2f(u2.z), b2f(u2.w)};
  float ub3[4] = {b2f(u3.x), b2f(u3.y), b2f(u3.z), b2f(u3.w)};
  float bbv[4] = {bb.x, bb.y, bb.z, bb.w};
  ushort ov[4];
#pragma unroll
  for (int j = 0; j < 4; ++j) {
    float4 wj = *(const float4*)(cw + (d0 + j) * 4);
    float acc = bbv[j];
    acc = fmaf(wj.w, ub0[j], acc);
    acc = fmaf(wj.z, ub1[j], acc);
    acc = fmaf(wj.y, ub2[j], acc);
    acc = fmaf(wj.x, ub3[j], acc);
    ov[j] = f2b(acc * sigmoidf_(acc));
  }
  ushort4 o;
  o.x = ov[0]; o.y = ov[1]; o.z = ov[2]; o.w = ov[3];
  *(ushort4*)(uc_bf + dir * USLAB + (long)r * D_INNER + d0) = o;
}

// Decay powers E^(s+1), s=0..15, from E = exp(-dt).
#define EP_FAST(dt, Ep)                                        \
  {                                                            \
    float E1 = __expf(-(dt));                                  \
    float E2 = E1 * E1, E4 = E2 * E2, E8 = E4 * E4;            \
    Ep[0] = E1;  Ep[1] = E2;      Ep[2] = E2 * E1;             \
    Ep[3] = E4;  Ep[4] = E4 * E1; Ep[5] = E4 * E2;             \
    Ep[6] = E4 * Ep[2]; Ep[7] = E8;  Ep[8] = E8 * E1;          \
    Ep[9] = E8 * E2; Ep[10] = E8 * Ep[2]; Ep[11] = E8 * E4;    \
    Ep[12] = E8 * Ep[4]; Ep[13] = E8 * Ep[5];                  \
    Ep[14] = E8 * Ep[6]; Ep[15] = E8 * E8;                     \
  }

__device__ __forceinline__ bool a_is_arange(const float* Ar) {
  bool ok = true;
#pragma unroll
  for (int s = 0; s < D_STATE; ++s)
    ok = ok && (fabsf(Ar[s] + (float)(s + 1)) <= 1e-3f * (float)(s + 1));
  return ok;
}

// ---------------- chunked selective scan (both dirs in one grid) -----------
__global__ __launch_bounds__(256) void scan_partA(
    const ushort* __restrict__ delta_bf,
    const ushort* __restrict__ ucv_bf,
    const ushort* __restrict__ dblb,
    const float* __restrict__ A_log_f, const float* __restrict__ A_log_b,
    ushort* __restrict__ hend,
    float* __restrict__ dtsum_buf)
{
  __shared__ float bc[CL][16];
  long idx = (long)blockIdx.x * 256 + threadIdx.x;
  int d = (int)idx & 1023;
  int c = ((int)idx >> 10) & (CH - 1);
  int b = ((int)idx >> 16) & 7;
  int dir = (int)(idx >> 19);
  const long r0 = (long)b * SEQ + c * CL;
  const ushort* dblp = dblb + (long)dir * NROWS * 64;
  {
    int tt = threadIdx.x >> 4, ss = threadIdx.x & 15;
    bc[tt][ss] = b2f(dblp[(r0 + tt) * 64 + 32 + ss]);
  }
  const float* Alog = dir ? A_log_b : A_log_f;
  const ushort* dp = delta_bf + dir * USLAB;
  const ushort* up = ucv_bf + dir * USLAB;
  float Ar[D_STATE];
#pragma unroll
  for (int s = 0; s < D_STATE; ++s) Ar[s] = -__expf(Alog[d * D_STATE + s]);
  const bool fast = a_is_arange(Ar);
  float h[D_STATE] = {0.f};
  float dtsum = 0.f;
  __syncthreads();

  if (fast) {
    for (int t = 0; t < CL; ++t) {
      long r = r0 + t;
      float dt = b2f(dp[r * 1024 + d]);
      float u  = b2f(up[r * 1024 + d]);
      float du = dt * u;
      dtsum += dt;
      float Ep[16];
      EP_FAST(dt, Ep);
#pragma unroll
      for (int s = 0; s < D_STATE; ++s)
        h[s] = fmaf(h[s], Ep[s], du * bc[t][s]);
    }
  } else {
    for (int t = 0; t < CL; ++t) {
      long r = r0 + t;
      float dt = b2f(dp[r * 1024 + d]);
      float u  = b2f(up[r * 1024 + d]);
      float du = dt * u;
      dtsum += dt;
#pragma unroll
      for (int s = 0; s < D_STATE; ++s)
        h[s] = fmaf(h[s], __expf(dt * Ar[s]), du * bc[t][s]);
    }
  }
  long base = ((long)((dir * 8 + b) * CH + c) * D_STATE) * 1024 + d;
#pragma unroll
  for (int s = 0; s < D_STATE; ++s) hend[base + s * 1024] = f2b(h[s]);
  dtsum_buf[(long)((dir * 8 + b) * CH + c) * 1024 + d] = dtsum;
}

__global__ __launch_bounds__(256) void scan_partB(
    ushort* __restrict__ hend,
    const float* __restrict__ dtsum_buf,
    const float* __restrict__ A_log_f, const float* __restrict__ A_log_b)
{
  long idx = (long)blockIdx.x * 256 + threadIdx.x;
  int d = (int)idx & 1023;
  int s = ((int)idx >> 10) & 15;
  int b = ((int)idx >> 14) & 7;
  int dir = (int)(idx >> 17);
  const float* Alog = dir ? A_log_b : A_log_f;
  float Ars = -__expf(Alog[d * D_STATE + s]);
  float H = 0.f;
  for (int c = 0; c < CH; ++c) {
    long off = ((long)((dir * 8 + b) * CH + c) * D_STATE + s) * 1024 + d;
    float he = b2f(hend[off]);
    float P = __expf(Ars * dtsum_buf[(long)((dir * 8 + b) * CH + c) * 1024 + d]);
    hend[off] = f2b(H);
    H = fmaf(P, H, he);
  }
}

__global__ __launch_bounds__(256) void scan_partC(
    const ushort* __restrict__ delta_bf,
    const ushort* __restrict__ ucv_bf,
    const ushort* __restrict__ dblb,
    const float* __restrict__ A_log_f, const float* __restrict__ A_log_b,
    const float* __restrict__ Dp_f, const float* __restrict__ Dp_b,
    const ushort* __restrict__ zsilu_bf,
    const ushort* __restrict__ hinit,
    ushort* __restrict__ ydz_bf)
{
  __shared__ float bc[CL][32];
  long idx = (long)blockIdx.x * 256 + threadIdx.x;
  int d = (int)idx & 1023;
  int c = ((int)idx >> 10) & (CH - 1);
  int b = ((int)idx >> 16) & 7;
  int dir = (int)(idx >> 19);
  const long r0 = (long)b * SEQ + c * CL;
  const ushort* dblp = dblb + (long)dir * NROWS * 64;
  {
    int tt = threadIdx.x >> 4, cc = (threadIdx.x & 15) * 2;
    ushort2 v = *(const ushort2*)&dblp[(r0 + tt) * 64 + 32 + cc];
    bc[tt][cc] = b2f(v.x); bc[tt][cc + 1] = b2f(v.y);
  }
  const float* Alog = dir ? A_log_b : A_log_f;
  const ushort* dp = delta_bf + dir * USLAB;
  const ushort* up = ucv_bf + dir * USLAB;
  const ushort* zp = zsilu_bf + dir * USLAB;
  ushort* yp = ydz_bf + dir * USLAB;
  float Ar[D_STATE];
#pragma unroll
  for (int s = 0; s < D_STATE; ++s) Ar[s] = -__expf(Alog[d * D_STATE + s]);
  const bool fast = a_is_arange(Ar);
  float h[D_STATE];
  long base = ((long)((dir * 8 + b) * CH + c) * D_STATE) * 1024 + d;
#pragma unroll
  for (int s = 0; s < D_STATE; ++s) h[s] = b2f(hinit[base + s * 1024]);
  float Dd = (dir ? Dp_b : Dp_f)[d];
  __syncthreads();

  if (fast) {
    for (int t = 0; t < CL; ++t) {
      long r = r0 + t;
      float dt = b2f(dp[r * 1024 + d]);
      float u  = b2f(up[r * 1024 + d]);
      float du = dt * u;
      float Ep[16];
      EP_FAST(dt, Ep);
      float y = 0.f;
#pragma unroll
      for (int s = 0; s < D_STATE; ++s) {
        h[s] = fmaf(h[s], Ep[s], du * bc[t][s]);
        y = fmaf(h[s], bc[t][16 + s], y);
      }
      float zs = b2f(zp[r * 1024 + d]);
      float yv = fmaf(u, Dd, y);
      yp[r * 1024 + d] = f2b(yv * zs);
    }
  } else {
    for (int t = 0; t < CL; ++t) {
      long r = r0 + t;
      float dt = b2f(dp[r * 1024 + d]);
      float u  = b2f(up[r * 1024 + d]);
      float du = dt * u;
      float y = 0.f;
#pragma unroll
      for (int s = 0; s < D_STATE; ++s) {
        h[s] = fmaf(h[s], __expf(dt * Ar[s]), du * bc[t][s]);
        y = fmaf(h[s], bc[t][16 + s], y);
      }
      float zs = b2f(zp[r * 1024 + d]);
      float yv = fmaf(u, Dd, y);
      yp[r * 1024 + d] = f2b(yv * zs);
    }
  }
}

extern "C" void kernel_launch(void* const* d_in, const int* in_sizes, int n_in,
                              void* d_out, int out_size, void* d_ws, size_t ws_size,
                              hipStream_t stream)
{
  const float* x = (const float*)d_in[0];
  float* out = (float*)d_out;
  char* ws = (char*)d_ws;
  ushort* zsilu  = (ushort*)(ws);                     // 32 MiB
  ushort* ucv    = (ushort*)(ws + (32ul << 20));      // 32 MiB (=ydz)
  ushort* u_bf   = (ushort*)(ws + (64ul << 20));      // 32 MiB (=delta)
  ushort* hend   = (ushort*)(ws + (96ul << 20));      // 32 MiB
  float*  dtsum  = (float*)(ws + (128ul << 20));      //  4 MiB
  ushort* dblb   = (ushort*)(ws + (132ul << 20));     //  2 MiB
  ushort* out_wb = (ushort*)(ws + (134ul << 20));     //  2 MiB
  ushort* xbf    = hend;                              // transient in hend slab
  ushort* in_wb  = hend + (8ul << 19);
  ushort* xp_wb  = hend + (12ul << 19);
  ushort* dt_wb  = xp_wb + 131072;
  ushort* delta  = u_bf;
  ushort* ydz    = ucv;

  ConvArgs ca;
  int bcur = 0, si = 0;
  auto addseg = [&](const float* s, ushort* d, int nelem) {
    ca.seg[si].s = (const float4*)s; ca.seg[si].d = (ushort4*)d;
    ca.seg[si].n4 = nelem / 4; ca.seg[si].bstart = bcur;
    bcur += (nelem / 4 + 255) / 256; ++si;
  };
  addseg(x, xbf, NROWS * D_MODEL);
  addseg((const float*)d_in[1], in_wb, 2048 * 512);
  addseg((const float*)d_in[10], in_wb + 2048 * 512, 2048 * 512);
  addseg((const float*)d_in[9], out_wb, 512 * 1024);
  addseg((const float*)d_in[18], out_wb + 512 * 1024, 512 * 1024);
  addseg((const float*)d_in[4], xp_wb, 64 * 1024);
  addseg((const float*)d_in[13], xp_wb + 65536, 64 * 1024);
  addseg((const float*)d_in[5], dt_wb, 1024 * 32);
  addseg((const float*)d_in[14], dt_wb + 32768, 1024 * 32);

  dim3 blk(256);
  convert_all<<<dim3(bcur), blk, 0, stream>>>(ca);

  // 1) merged in_proj (vectorized epilogue)
  inproj256<<<dim3(4096 / 256, NROWS / 256), dim3(512), 0, stream>>>(
      xbf, D_MODEL, in_wb, D_MODEL, u_bf, zsilu, D_MODEL);
  // 2) conv + silu, both dirs
  conv_silu<<<dim3(2 * NROWS), blk, 0, stream>>>(
      u_bf, (const float*)d_in[2], (const float*)d_in[11],
      (const float*)d_in[3], (const float*)d_in[12], ucv);
  // 3) x_proj, both dirs block-diag
  gemm_bf16<64, 64, 2, 2, 4, 0, 1><<<dim3(1, 256), blk, 0, stream>>>(
      ucv, D_INNER, nullptr, xp_wb, D_INNER, nullptr,
      nullptr, dblb, nullptr, 64, D_INNER, nullptr, nullptr, 65536, 0, 0);
  // 4) dt_proj + softplus, both dirs block-diag (vectorized epilogue)
  gemm_bf16<128, 128, 2, 2, 1, 0, 1><<<dim3(8, 128), blk, 0, stream>>>(
      dblb, 64, nullptr, dt_wb, DT_RANK, nullptr,
      nullptr, delta, nullptr, D_INNER, DT_RANK,
      (const float*)d_in[6], (const float*)d_in[15], 32768, 0, 0);
  // 5) chunked scan, both dirs
  const float* Alf = (const float*)d_in[7];
  const float* Alb = (const float*)d_in[16];
  scan_partA<<<dim3(2 * BATCH * CH * 1024 / 256), blk, 0, stream>>>(
      delta, ucv, dblb, Alf, Alb, hend, dtsum);
  scan_partB<<<dim3(2 * BATCH * 16 * 1024 / 256), blk, 0, stream>>>(
      hend, dtsum, Alf, Alb);
  scan_partC<<<dim3(2 * BATCH * CH * 1024 / 256), blk, 0, stream>>>(
      delta, ucv, dblb, Alf, Alb,
      (const float*)d_in[8], (const float*)d_in[17], zsilu, hend, ydz);
  // 6) out_proj, both dirs in one K=2048 dispatch
  gemm_bf16<128, 128, 2, 2, 0, 1, 0><<<dim3(4, 64), blk, 0, stream>>>(
      ydz, D_INNER, ydz + USLAB, out_wb, D_INNER, out_wb + 512 * 1024,
      out, nullptr, nullptr, D_MODEL, 2 * D_INNER, nullptr, nullptr, 0, 0, 0);
}